// Round 3
// baseline (9120.507 us; speedup 1.0000x reference)
//
#include <hip/hip_runtime.h>
#include <math.h>

#define HID    2048
#define CONVD  8192
#define VDIM   4096
#define SEG    512
#define SEGTOK 2048     // 4 strips * SEG
#define NSEG   4

__device__ __forceinline__ float dot4(float4 a, float4 b) {
  return fmaf(a.x, b.x, fmaf(a.y, b.y, fmaf(a.z, b.z, a.w * b.w)));
}
__device__ __forceinline__ float sigmoidf_(float x) { return 1.f / (1.f + __expf(-x)); }
// local segment row (b*512 + r) -> global token row (b*2048 + t_off + r)
__device__ __forceinline__ int gmap(int m, int t_off) {
  return ((m >> 9) << 11) + t_off + (m & 511);
}

// ---------------- fp32 tiled GEMM with optional segment row-mapping ----------------
// C[m, n] (+map) = A[m(+map), :K] @ B[:K, n]
template<int MAPA, int MAPC>
__global__ __launch_bounds__(256)
void sgemm_seg(const float* __restrict__ A, const float* __restrict__ B,
               float* __restrict__ C, int N, int K, int t_off) {
  __shared__ float As[16][132];
  __shared__ float Bs[16][132];
  const int tid = threadIdx.x;
  const int row0 = blockIdx.y * 128, col0 = blockIdx.x * 128;
  const int lr = tid >> 1, ls = (tid & 1) * 8;     // A loader: 1 row, 8 cols
  const int br = tid >> 4, bc = (tid & 15) * 8;    // B loader
  const int tr = (tid >> 4) * 8, tc = (tid & 15) * 8;
  const int arow = MAPA ? gmap(row0 + lr, t_off) : (row0 + lr);
  const float* Arow = A + (size_t)arow * K;
  float acc[8][8];
  #pragma unroll
  for (int i = 0; i < 8; ++i)
    #pragma unroll
    for (int j = 0; j < 8; ++j) acc[i][j] = 0.f;
  for (int k0 = 0; k0 < K; k0 += 16) {
    float4 a0 = *(const float4*)(Arow + k0 + ls);
    float4 a1 = *(const float4*)(Arow + k0 + ls + 4);
    float4 b0 = *(const float4*)(B + (size_t)(k0 + br) * N + col0 + bc);
    float4 b1 = *(const float4*)(B + (size_t)(k0 + br) * N + col0 + bc + 4);
    As[ls + 0][lr] = a0.x; As[ls + 1][lr] = a0.y; As[ls + 2][lr] = a0.z; As[ls + 3][lr] = a0.w;
    As[ls + 4][lr] = a1.x; As[ls + 5][lr] = a1.y; As[ls + 6][lr] = a1.z; As[ls + 7][lr] = a1.w;
    *(float4*)&Bs[br][bc] = b0;
    *(float4*)&Bs[br][bc + 4] = b1;
    __syncthreads();
    #pragma unroll
    for (int kk = 0; kk < 16; ++kk) {
      float a[8], b[8];
      *(float4*)(a) = *(const float4*)&As[kk][tr];
      *(float4*)(a + 4) = *(const float4*)&As[kk][tr + 4];
      *(float4*)(b) = *(const float4*)&Bs[kk][tc];
      *(float4*)(b + 4) = *(const float4*)&Bs[kk][tc + 4];
      #pragma unroll
      for (int i = 0; i < 8; ++i)
        #pragma unroll
        for (int j = 0; j < 8; ++j) acc[i][j] = fmaf(a[i], b[j], acc[i][j]);
    }
    __syncthreads();
  }
  #pragma unroll
  for (int i = 0; i < 8; ++i) {
    const int crow = MAPC ? gmap(row0 + tr + i, t_off) : (row0 + tr + i);
    float4 c0 = make_float4(acc[i][0], acc[i][1], acc[i][2], acc[i][3]);
    float4 c1 = make_float4(acc[i][4], acc[i][5], acc[i][6], acc[i][7]);
    *(float4*)(C + (size_t)crow * N + col0 + tc) = c0;
    *(float4*)(C + (size_t)crow * N + col0 + tc + 4) = c1;
  }
}

// ---------------- zero the parity-0 conv halo ----------------
__global__ __launch_bounds__(256)
void zero_halo(float* __restrict__ H) {
  const int i = blockIdx.x * 256 + threadIdx.x;   // 24576 float4 = 98304 floats
  ((float4*)H)[i] = make_float4(0.f, 0.f, 0.f, 0.f);
}

// ---------------- causal depthwise conv1d (K=4) + SiLU, segmented ----------------
__global__ __launch_bounds__(256)
void conv_seg(const float* __restrict__ Mseg, const float* __restrict__ w,
              float* __restrict__ Cseg, float* __restrict__ H, int par) {
  const int idx = blockIdx.x * 256 + threadIdx.x;   // one float4 per thread
  const int c4 = idx & 2047;                        // 2048 float4 per token row
  const int tok = idx >> 11;                        // local token 0..2047
  const int b = tok >> 9, tl = tok & 511;
  const int ch = c4 * 4;
  float wt[4][4];
  #pragma unroll
  for (int m = 0; m < 4; ++m) {
    float4 wm = *(const float4*)(w + (size_t)(ch + m) * 4);
    wt[m][0] = wm.x; wt[m][1] = wm.y; wt[m][2] = wm.z; wt[m][3] = wm.w;
  }
  const float* Hrd = H + (size_t)par * (4 * 3 * CONVD);
  float*       Hwr = H + (size_t)(par ^ 1) * (4 * 3 * CONVD);
  float4 acc = make_float4(0.f, 0.f, 0.f, 0.f);
  float4 x3 = make_float4(0.f, 0.f, 0.f, 0.f);
  #pragma unroll
  for (int j = 0; j < 4; ++j) {
    const int ts = tl + j - 3;
    float4 x;
    if (ts >= 0) x = *(const float4*)(Mseg + (size_t)(b * SEG + ts) * CONVD + ch);
    else         x = *(const float4*)(Hrd + (size_t)(b * 3 + 3 + ts) * CONVD + ch);
    if (j == 3) x3 = x;
    acc.x = fmaf(x.x, wt[0][j], acc.x);
    acc.y = fmaf(x.y, wt[1][j], acc.y);
    acc.z = fmaf(x.z, wt[2][j], acc.z);
    acc.w = fmaf(x.w, wt[3][j], acc.w);
  }
  acc.x *= sigmoidf_(acc.x); acc.y *= sigmoidf_(acc.y);
  acc.z *= sigmoidf_(acc.z); acc.w *= sigmoidf_(acc.w);
  *(float4*)(Cseg + (size_t)tok * CONVD + ch) = acc;
  if (tl >= SEG - 3)   // save last-3-token mixed rows as next segment's halo
    *(float4*)(Hwr + (size_t)(b * 3 + tl - (SEG - 3)) * CONVD + ch) = x3;
}

// ---------------- b,a projections -> beta, g (segmented) ----------------
__global__ __launch_bounds__(256)
void ba_seg(const float* __restrict__ hs, const float* __restrict__ Wb,
            const float* __restrict__ Wa, const float* __restrict__ dtb,
            const float* __restrict__ Alog, float* __restrict__ beta,
            float* __restrict__ g, int t_off) {
  __shared__ float row[2048];
  __shared__ float red[4][64];
  const int tok = blockIdx.x;                 // local 0..2047
  const int tid = threadIdx.x;
  const float* hr = hs + (size_t)gmap(tok, t_off) * HID;
  for (int i = tid; i < 512; i += 256) ((float4*)row)[i] = ((const float4*)hr)[i];
  __syncthreads();
  const int o = tid & 63, kg = tid >> 6;
  const float* W = (o < 32) ? Wb : Wa;
  const int c = o & 31;
  float s = 0.f;
  const int k0 = kg * 512;
  for (int k = k0; k < k0 + 512; ++k) s = fmaf(row[k], W[(size_t)k * 32 + c], s);
  red[kg][o] = s;
  __syncthreads();
  if (tid < 64) {
    float v = red[0][tid] + red[1][tid] + red[2][tid] + red[3][tid];
    if (tid < 32) {
      beta[(size_t)tok * 32 + tid] = 1.f / (1.f + __expf(-v));
    } else {
      const int c2 = tid - 32;
      const float x = v + dtb[c2];
      const float sp = (x > 20.f) ? x : log1pf(__expf(x));
      g[(size_t)tok * 32 + c2] = -__expf(Alog[c2]) * sp;
    }
  }
}

// ---------------- gated delta rule core (segmented, S carried in global) ----------------
// grid: 256 blocks = ((b*32+h)*2 + half) ; 512 threads
__global__ __launch_bounds__(512, 1)
void core_seg(const float* __restrict__ Cseg, const float* __restrict__ gbuf,
              const float* __restrict__ bbuf, float* __restrict__ Oseg,
              float* __restrict__ Sstate, int seg) {
  __shared__ float St[64][132];   // S^T : [v-col c][d]
  __shared__ float ks[64][132];
  __shared__ float qs[64][132];
  __shared__ float Am[64][68];
  __shared__ float At[64][68];
  __shared__ float vn[64][67];
  __shared__ float gcs[64], egp[64], egl[64], betas[64];

  const int tid = threadIdx.x;
  const int lane = tid & 63, wv = tid >> 6;
  const int bid = blockIdx.x;
  const int half = bid & 1, bh = bid >> 1;
  const int b = bh >> 5, h = bh & 31, hk = h >> 1;

  const float* qg = Cseg + (size_t)b * SEG * CONVD + (size_t)hk * 128;
  const float* kg = qg + 2048;
  const float* vg = Cseg + (size_t)b * SEG * CONVD + 4096 + (size_t)h * 128 + half * 64;
  const float* gg = gbuf + (size_t)b * SEG * 32 + h;
  const float* bb = bbuf + (size_t)b * SEG * 32 + h;
  float* og = Oseg + (size_t)b * SEG * VDIM + (size_t)h * 128 + half * 64;
  float* Sg = Sstate + (size_t)bid * 8192;

  if (seg == 0) {
    for (int i = tid; i < 64 * 132; i += 512) (&St[0][0])[i] = 0.f;
  } else {
    for (int i = tid; i < 8192; i += 512) St[i >> 7][i & 127] = Sg[i];
  }
  __syncthreads();

  for (int n = 0; n < SEG / 64; ++n) {
    const int t0 = n * 64;
    // ---------- load: g-scan + normalized q,k ----------
    if (wv == 0) {
      float gv = gg[(size_t)(t0 + lane) * 32];
      #pragma unroll
      for (int off = 1; off < 64; off <<= 1) {
        float u = __shfl_up(gv, off);
        if (lane >= off) gv += u;
      }
      const float gl = __shfl(gv, 63);
      gcs[lane] = gv;
      egp[lane] = __expf(gv);
      egl[lane] = __expf(gl - gv);
      betas[lane] = bb[(size_t)(t0 + lane) * 32];
    }
    {
      const int r = tid >> 3, j = tid & 7;
      const float* krow = kg + (size_t)(t0 + r) * CONVD + j * 16;
      const float* qrow = qg + (size_t)(t0 + r) * CONVD + j * 16;
      float4 kv[4], qv[4];
      float sk = 0.f, sq = 0.f;
      #pragma unroll
      for (int u = 0; u < 4; ++u) {
        kv[u] = *(const float4*)(krow + u * 4);
        qv[u] = *(const float4*)(qrow + u * 4);
        sk += dot4(kv[u], kv[u]);
        sq += dot4(qv[u], qv[u]);
      }
      #pragma unroll
      for (int off = 1; off < 8; off <<= 1) { sk += __shfl_xor(sk, off); sq += __shfl_xor(sq, off); }
      const float rk = 1.f / sqrtf(sk + 1e-6f);
      const float rq = 0.08838834764831845f / sqrtf(sq + 1e-6f);  // * Dk^-0.5
      #pragma unroll
      for (int u = 0; u < 4; ++u) {
        float4 t = kv[u];
        t.x *= rk; t.y *= rk; t.z *= rk; t.w *= rk;
        *(float4*)&ks[r][j * 16 + u * 4] = t;
        float4 t2 = qv[u];
        t2.x *= rq; t2.y *= rq; t2.z *= rq; t2.w *= rq;
        *(float4*)&qs[r][j * 16 + u * 4] = t2;
      }
    }
    __syncthreads();

    // ---------- A (strict lower) & attn (lower incl diag) ----------
    {
      const int i0 = (tid >> 5) * 4;
      const int ja = tid & 31, jb = ja + 32;
      float kk[4][2] = {{0.f}}, qk[4][2] = {{0.f}};
      #pragma unroll 8
      for (int d0 = 0; d0 < 128; d0 += 4) {
        const float4 k0 = *(const float4*)&ks[ja][d0];
        const float4 k1 = *(const float4*)&ks[jb][d0];
        #pragma unroll
        for (int r = 0; r < 4; ++r) {
          const float4 ki = *(const float4*)&ks[i0 + r][d0];
          const float4 qi = *(const float4*)&qs[i0 + r][d0];
          kk[r][0] += dot4(ki, k0);
          kk[r][1] += dot4(ki, k1);
          qk[r][0] += dot4(qi, k0);
          qk[r][1] += dot4(qi, k1);
        }
      }
      #pragma unroll
      for (int r = 0; r < 4; ++r) {
        const int i = i0 + r;
        const float gi = gcs[i], bi = betas[i];
        float e = __expf(gi - gcs[ja]);
        Am[i][ja] = (i > ja) ? -bi * e * kk[r][0] : 0.f;
        At[i][ja] = (i >= ja) ? e * qk[r][0] : 0.f;
        e = __expf(gi - gcs[jb]);
        Am[i][jb] = (i > jb) ? -bi * e * kk[r][1] : 0.f;
        At[i][jb] = (i >= jb) ? e * qk[r][1] : 0.f;
      }
    }
    // ---------- u = beta*v - (beta e^gc k) @ S ----------
    {
      const int i0 = (tid >> 5) * 4;
      const int ca = tid & 31, cb = ca + 32;
      float acc[4][2] = {{0.f}};
      #pragma unroll 8
      for (int d0 = 0; d0 < 128; d0 += 4) {
        const float4 s0 = *(const float4*)&St[ca][d0];
        const float4 s1 = *(const float4*)&St[cb][d0];
        #pragma unroll
        for (int r = 0; r < 4; ++r) {
          const float4 kr = *(const float4*)&ks[i0 + r][d0];
          acc[r][0] += dot4(kr, s0);
          acc[r][1] += dot4(kr, s1);
        }
      }
      #pragma unroll
      for (int r = 0; r < 4; ++r) {
        const int i = i0 + r;
        const float be = betas[i];
        const float sc = be * egp[i];
        const float v0 = vg[(size_t)(t0 + i) * CONVD + ca];
        const float v1 = vg[(size_t)(t0 + i) * CONVD + cb];
        vn[i][ca] = fmaf(be, v0, -sc * acc[r][0]);
        vn[i][cb] = fmaf(be, v1, -sc * acc[r][1]);
      }
    }
    __syncthreads();

    // ---------- forward substitution: v_new = (I-A)^{-1} u ----------
    {
      const int c = wv * 8 + (lane >> 3);
      const int jl = lane & 7;
      for (int i = 1; i < 64; ++i) {
        float p = 0.f;
        for (int j = jl; j < i; j += 8) p = fmaf(Am[i][j], vn[j][c], p);
        p += __shfl_xor(p, 1);
        p += __shfl_xor(p, 2);
        p += __shfl_xor(p, 4);
        if (jl == 0) vn[i][c] += p;
      }
    }
    __syncthreads();

    // ---------- out = (q e^gc) @ S + attn @ v_new ----------
    {
      const int i0 = (tid >> 5) * 4;
      const int ca = tid & 31, cb = ca + 32;
      float ov[4][2] = {{0.f}};
      #pragma unroll 8
      for (int d0 = 0; d0 < 128; d0 += 4) {
        const float4 s0 = *(const float4*)&St[ca][d0];
        const float4 s1 = *(const float4*)&St[cb][d0];
        #pragma unroll
        for (int r = 0; r < 4; ++r) {
          const float4 qr = *(const float4*)&qs[i0 + r][d0];
          ov[r][0] += dot4(qr, s0);
          ov[r][1] += dot4(qr, s1);
        }
      }
      #pragma unroll
      for (int r = 0; r < 4; ++r) { ov[r][0] *= egp[i0 + r]; ov[r][1] *= egp[i0 + r]; }
      #pragma unroll 4
      for (int j0 = 0; j0 < 64; j0 += 4) {
        float a_[4][4];
        #pragma unroll
        for (int r = 0; r < 4; ++r) {
          float4 t = *(const float4*)&At[i0 + r][j0];
          a_[r][0] = t.x; a_[r][1] = t.y; a_[r][2] = t.z; a_[r][3] = t.w;
        }
        #pragma unroll
        for (int jj = 0; jj < 4; ++jj) {
          const float v0 = vn[j0 + jj][ca];
          const float v1 = vn[j0 + jj][cb];
          #pragma unroll
          for (int r = 0; r < 4; ++r) {
            ov[r][0] = fmaf(a_[r][jj], v0, ov[r][0]);
            ov[r][1] = fmaf(a_[r][jj], v1, ov[r][1]);
          }
        }
      }
      #pragma unroll
      for (int r = 0; r < 4; ++r) {
        og[(size_t)(t0 + i0 + r) * VDIM + ca] = ov[r][0];
        og[(size_t)(t0 + i0 + r) * VDIM + cb] = ov[r][1];
      }
    }
    __syncthreads();

    // ---------- S = e^gl * S + (k e^{gl-gc})^T @ v_new ----------
    {
      const int ca = tid & 31, cb = ca + 32;
      const int d0 = (tid >> 5) * 8;
      const float egall = __expf(gcs[63]);
      float accA[8] = {0.f, 0.f, 0.f, 0.f, 0.f, 0.f, 0.f, 0.f};
      float accB[8] = {0.f, 0.f, 0.f, 0.f, 0.f, 0.f, 0.f, 0.f};
      #pragma unroll 4
      for (int i = 0; i < 64; ++i) {
        const float w = egl[i];
        const float x0 = vn[i][ca] * w;
        const float x1 = vn[i][cb] * w;
        const float4 k0 = *(const float4*)&ks[i][d0];
        const float4 k1 = *(const float4*)&ks[i][d0 + 4];
        accA[0] = fmaf(x0, k0.x, accA[0]); accA[1] = fmaf(x0, k0.y, accA[1]);
        accA[2] = fmaf(x0, k0.z, accA[2]); accA[3] = fmaf(x0, k0.w, accA[3]);
        accA[4] = fmaf(x0, k1.x, accA[4]); accA[5] = fmaf(x0, k1.y, accA[5]);
        accA[6] = fmaf(x0, k1.z, accA[6]); accA[7] = fmaf(x0, k1.w, accA[7]);
        accB[0] = fmaf(x1, k0.x, accB[0]); accB[1] = fmaf(x1, k0.y, accB[1]);
        accB[2] = fmaf(x1, k0.z, accB[2]); accB[3] = fmaf(x1, k0.w, accB[3]);
        accB[4] = fmaf(x1, k1.x, accB[4]); accB[5] = fmaf(x1, k1.y, accB[5]);
        accB[6] = fmaf(x1, k1.z, accB[6]); accB[7] = fmaf(x1, k1.w, accB[7]);
      }
      float4 s;
      s = *(float4*)&St[ca][d0];
      s.x = fmaf(s.x, egall, accA[0]); s.y = fmaf(s.y, egall, accA[1]);
      s.z = fmaf(s.z, egall, accA[2]); s.w = fmaf(s.w, egall, accA[3]);
      *(float4*)&St[ca][d0] = s;
      s = *(float4*)&St[ca][d0 + 4];
      s.x = fmaf(s.x, egall, accA[4]); s.y = fmaf(s.y, egall, accA[5]);
      s.z = fmaf(s.z, egall, accA[6]); s.w = fmaf(s.w, egall, accA[7]);
      *(float4*)&St[ca][d0 + 4] = s;
      s = *(float4*)&St[cb][d0];
      s.x = fmaf(s.x, egall, accB[0]); s.y = fmaf(s.y, egall, accB[1]);
      s.z = fmaf(s.z, egall, accB[2]); s.w = fmaf(s.w, egall, accB[3]);
      *(float4*)&St[cb][d0] = s;
      s = *(float4*)&St[cb][d0 + 4];
      s.x = fmaf(s.x, egall, accB[4]); s.y = fmaf(s.y, egall, accB[5]);
      s.z = fmaf(s.z, egall, accB[6]); s.w = fmaf(s.w, egall, accB[7]);
      *(float4*)&St[cb][d0 + 4] = s;
    }
    __syncthreads();
  }

  // spill S for next segment
  for (int i = tid; i < 8192; i += 512) Sg[i] = St[i >> 7][i & 127];
}

// ---------------- gated RMSNorm (in-place on core out, segmented) ----------------
__global__ __launch_bounds__(256)
void rms_seg(float* __restrict__ core, const float* __restrict__ z,
             const float* __restrict__ nw) {
  const int tid = threadIdx.x;
  const int row = blockIdx.x * 8 + (tid >> 5);   // local (tok*32+h) row
  const int lc = tid & 31;
  const size_t off = (size_t)row * 128 + lc * 4;
  float4 cv4 = *(const float4*)(core + off);
  float4 zv = *(const float4*)(z + off);
  zv.x *= sigmoidf_(zv.x); zv.y *= sigmoidf_(zv.y);
  zv.z *= sigmoidf_(zv.z); zv.w *= sigmoidf_(zv.w);
  float4 gt = make_float4(cv4.x * zv.x, cv4.y * zv.y, cv4.z * zv.z, cv4.w * zv.w);
  float ss = gt.x * gt.x + gt.y * gt.y + gt.z * gt.z + gt.w * gt.w;
  #pragma unroll
  for (int off2 = 1; off2 < 32; off2 <<= 1) ss += __shfl_xor(ss, off2);
  const float rn = 1.f / sqrtf(ss * (1.f / 128.f) + 1e-6f);
  float4 wn = *(const float4*)(nw + lc * 4);
  float4 r = make_float4(gt.x * rn * wn.x, gt.y * rn * wn.y, gt.z * rn * wn.z, gt.w * rn * wn.w);
  *(float4*)(core + off) = r;
}

extern "C" void kernel_launch(void* const* d_in, const int* in_sizes, int n_in,
                              void* d_out, int out_size, void* d_ws, size_t ws_size,
                              hipStream_t stream) {
  (void)in_sizes; (void)n_in; (void)out_size;
  const float* hs    = (const float*)d_in[0];
  const float* Wqkv  = (const float*)d_in[1];
  const float* Wz    = (const float*)d_in[2];
  const float* Wb    = (const float*)d_in[3];
  const float* Wa    = (const float*)d_in[4];
  const float* convw = (const float*)d_in[5];
  const float* dtb   = (const float*)d_in[6];
  const float* Alog  = (const float*)d_in[7];
  const float* normw = (const float*)d_in[8];
  const float* Wout  = (const float*)d_in[9];
  float* out = (float*)d_out;

  // workspace plan (peak 137.3 MiB):
  //   A [0, 64Mi)      : mixed_seg (2048x8192) -> later z_seg (2048x4096) + O_seg (2048x4096)
  //   B [64Mi, 128Mi)  : conv_seg  (2048x8192)
  //   S [128Mi, +8Mi)  : delta-rule state, 256 blocks x 64x128
  //   beta/g           : 2048x32 each
  //   H                : conv halo ping-pong 2x4x3x8192
  char* ws = (char*)d_ws;
  const size_t OFF_B    = 67108864;
  const size_t OFF_S    = 134217728;
  const size_t OFF_BETA = 142606336;
  const size_t OFF_G    = 142868480;
  const size_t OFF_H    = 143130624;
  const size_t NEED     = 143917056;
  if (ws_size < NEED) return;   // clean validation failure instead of OOB crash

  float* Abuf  = (float*)ws;
  float* Bbuf  = (float*)(ws + OFF_B);
  float* Sbuf  = (float*)(ws + OFF_S);
  float* betab = (float*)(ws + OFF_BETA);
  float* gbuf  = (float*)(ws + OFF_G);
  float* Hbuf  = (float*)(ws + OFF_H);
  float* Zbuf  = Abuf;                    // reuse after conv consumes mixed_seg
  float* Obuf  = Abuf + 8388608;          // second 32 MiB of A

  zero_halo<<<96, 256, 0, stream>>>(Hbuf);

  for (int s = 0; s < NSEG; ++s) {
    const int t0 = s * SEG;
    // 1. mixed_seg = hs[seg rows] @ Wqkv
    sgemm_seg<1, 0><<<dim3(CONVD / 128, SEGTOK / 128), 256, 0, stream>>>(
        hs, Wqkv, Abuf, CONVD, HID, t0);
    // 2. causal conv + silu (with 3-token halo carry)
    conv_seg<<<(SEGTOK * (CONVD / 4)) / 256, 256, 0, stream>>>(
        Abuf, convw, Bbuf, Hbuf, s & 1);
    // 3. z_seg = hs[seg rows] @ Wz   (A region now free)
    sgemm_seg<1, 0><<<dim3(VDIM / 128, SEGTOK / 128), 256, 0, stream>>>(
        hs, Wz, Zbuf, VDIM, HID, t0);
    // 4. beta, g
    ba_seg<<<SEGTOK, 256, 0, stream>>>(hs, Wb, Wa, dtb, Alog, betab, gbuf, t0);
    // 5. gated delta rule core (state carried through Sbuf)
    core_seg<<<256, 512, 0, stream>>>(Bbuf, gbuf, betab, Obuf, Sbuf, s);
    // 6. gated RMSNorm in place on O
    rms_seg<<<(SEGTOK * 32) / 8, 256, 0, stream>>>(Obuf, Zbuf, normw);
    // 7. out[seg rows] = O @ Wout
    sgemm_seg<0, 1><<<dim3(HID / 128, SEGTOK / 128), 256, 0, stream>>>(
        Obuf, Wout, out, HID, VDIM, t0);
  }
}

// Round 4
// 4288.840 us; speedup vs baseline: 2.1266x; 2.1266x over previous
//
#include <hip/hip_runtime.h>
#include <math.h>

#define HID    2048
#define CONVD  8192
#define VDIM   4096
#define SEG    256
#define SEGTOK 1024    // 4 strips * SEG
#define NSEG   8

typedef __attribute__((ext_vector_type(8))) short short8_t;
typedef __attribute__((ext_vector_type(8))) unsigned short ushort8_t;
typedef __attribute__((ext_vector_type(4))) float f32x4;

__device__ __forceinline__ unsigned short f2bf(float f) {
  union { float f; unsigned u; } x; x.f = f;
  return (unsigned short)((x.u + 0x7fffu + ((x.u >> 16) & 1u)) >> 16);
}
__device__ __forceinline__ float bf2f(unsigned short b) {
  union { unsigned u; float f; } x; x.u = ((unsigned)b) << 16;
  return x.f;
}
__device__ __forceinline__ float sigmoidf_(float x) { return 1.f / (1.f + __expf(-x)); }
// local segment row (b*256 + r) -> global token row (b*2048 + t_off + r)
__device__ __forceinline__ int gmap(int m, int t_off) {
  return ((m >> 8) << 11) + t_off + (m & 255);
}

// ---------------- weight transpose + fp32->bf16: Wt[N][K] = bf16(W[K][N]) ----------------
__global__ __launch_bounds__(256)
void wtrans(const float* __restrict__ W, unsigned short* __restrict__ Wt, int K, int N) {
  __shared__ float t[32][33];
  const int n0 = blockIdx.x * 32, k0 = blockIdx.y * 32;
  const int tx = threadIdx.x & 31, ty = threadIdx.x >> 5;   // 32 x 8
  #pragma unroll
  for (int i = 0; i < 4; ++i)
    t[ty + i * 8][tx] = W[(size_t)(k0 + ty + i * 8) * N + n0 + tx];
  __syncthreads();
  #pragma unroll
  for (int i = 0; i < 4; ++i)
    Wt[(size_t)(n0 + ty + i * 8) * K + k0 + tx] = f2bf(t[tx][ty + i * 8]);
}

// ---------------- bf16 MFMA GEMM: C[M,N] = A[M,K] @ Bt[N,K]^T ----------------
// 128x128 tile, 4 waves (2x2 of 64x64), 16x16x32 MFMA, BK=32, reg-staged LDS.
template<int ABF16, int CBF16, int MAPA, int MAPC>
__global__ __launch_bounds__(256)
void gemm_bf16(const void* __restrict__ Av, const unsigned short* __restrict__ Bt,
               void* __restrict__ Cv, int N, int K, int t_off) {
  __shared__ unsigned short As[128][40];   // pad 40: row stride 80B, <=2-way conflicts
  __shared__ unsigned short Bs[128][40];
  const int tid = threadIdx.x;
  const int row0 = blockIdx.y * 128, col0 = blockIdx.x * 128;
  const int srow = tid >> 1, shalf = (tid & 1) * 16;   // staging: 2 threads/row, 16 elems each
  const int arow = MAPA ? gmap(row0 + srow, t_off) : (row0 + srow);
  const int brow = col0 + srow;
  const int wv = tid >> 6, lane = tid & 63;
  const int wr = (wv >> 1) * 64, wc = (wv & 1) * 64;
  const int lrow = lane & 15, lk = (lane >> 4) * 8, lrow4 = (lane >> 4) * 4;

  f32x4 acc[4][4];
  #pragma unroll
  for (int mi = 0; mi < 4; ++mi)
    #pragma unroll
    for (int ni = 0; ni < 4; ++ni) acc[mi][ni] = (f32x4){0.f, 0.f, 0.f, 0.f};

  for (int k0 = 0; k0 < K; k0 += 32) {
    // ---- stage A tile [128][32] ----
    if (ABF16) {
      const unsigned short* ap = (const unsigned short*)Av + (size_t)arow * K + k0 + shalf;
      ushort8_t a0 = *(const ushort8_t*)ap;
      ushort8_t a1 = *(const ushort8_t*)(ap + 8);
      *(ushort8_t*)&As[srow][shalf] = a0;
      *(ushort8_t*)&As[srow][shalf + 8] = a1;
    } else {
      const float* ap = (const float*)Av + (size_t)arow * K + k0 + shalf;
      float4 f0 = *(const float4*)(ap);
      float4 f1 = *(const float4*)(ap + 4);
      float4 f2 = *(const float4*)(ap + 8);
      float4 f3 = *(const float4*)(ap + 12);
      ushort8_t u0, u1;
      u0[0] = f2bf(f0.x); u0[1] = f2bf(f0.y); u0[2] = f2bf(f0.z); u0[3] = f2bf(f0.w);
      u0[4] = f2bf(f1.x); u0[5] = f2bf(f1.y); u0[6] = f2bf(f1.z); u0[7] = f2bf(f1.w);
      u1[0] = f2bf(f2.x); u1[1] = f2bf(f2.y); u1[2] = f2bf(f2.z); u1[3] = f2bf(f2.w);
      u1[4] = f2bf(f3.x); u1[5] = f2bf(f3.y); u1[6] = f2bf(f3.z); u1[7] = f2bf(f3.w);
      *(ushort8_t*)&As[srow][shalf] = u0;
      *(ushort8_t*)&As[srow][shalf + 8] = u1;
    }
    // ---- stage B tile [128 cols][32 k] from Bt[N][K] ----
    {
      const unsigned short* bp = Bt + (size_t)brow * K + k0 + shalf;
      ushort8_t b0 = *(const ushort8_t*)bp;
      ushort8_t b1 = *(const ushort8_t*)(bp + 8);
      *(ushort8_t*)&Bs[srow][shalf] = b0;
      *(ushort8_t*)&Bs[srow][shalf + 8] = b1;
    }
    __syncthreads();
    short8_t af[4], bfr[4];
    #pragma unroll
    for (int mi = 0; mi < 4; ++mi) af[mi] = *(const short8_t*)&As[wr + mi * 16 + lrow][lk];
    #pragma unroll
    for (int ni = 0; ni < 4; ++ni) bfr[ni] = *(const short8_t*)&Bs[wc + ni * 16 + lrow][lk];
    #pragma unroll
    for (int mi = 0; mi < 4; ++mi)
      #pragma unroll
      for (int ni = 0; ni < 4; ++ni)
        acc[mi][ni] = __builtin_amdgcn_mfma_f32_16x16x32_bf16(af[mi], bfr[ni], acc[mi][ni], 0, 0, 0);
    __syncthreads();
  }
  // ---- epilogue: C/D layout col=lane&15, row=(lane>>4)*4+j ----
  #pragma unroll
  for (int mi = 0; mi < 4; ++mi) {
    #pragma unroll
    for (int j = 0; j < 4; ++j) {
      const int r = row0 + wr + mi * 16 + lrow4 + j;
      const int crow = MAPC ? gmap(r, t_off) : r;
      #pragma unroll
      for (int ni = 0; ni < 4; ++ni) {
        const float v = acc[mi][ni][j];
        const size_t ci = (size_t)crow * N + col0 + wc + ni * 16 + (lane & 15);
        if (CBF16) ((unsigned short*)Cv)[ci] = f2bf(v);
        else       ((float*)Cv)[ci] = v;
      }
    }
  }
}

// ---------------- zero the parity-0 conv halo (bf16) ----------------
__global__ __launch_bounds__(256)
void zero_halo(float* __restrict__ H) {
  const int i = blockIdx.x * 256 + threadIdx.x;   // 12288 float4 = 196608 B
  ((float4*)H)[i] = make_float4(0.f, 0.f, 0.f, 0.f);
}

// ---------------- causal depthwise conv1d (K=4) + SiLU, bf16 in/out ----------------
__global__ __launch_bounds__(256)
void conv_seg(const unsigned short* __restrict__ Mseg, const float* __restrict__ w,
              unsigned short* __restrict__ Cseg, unsigned short* __restrict__ H, int par) {
  const int idx = blockIdx.x * 256 + threadIdx.x;   // 4 channels per thread
  const int c4 = idx & 2047;
  const int tok = idx >> 11;                        // local token 0..SEGTOK-1
  const int b = tok >> 8, tl = tok & 255;
  const int ch = c4 * 4;
  float wt[4][4];
  #pragma unroll
  for (int m = 0; m < 4; ++m) {
    float4 wm = *(const float4*)(w + (size_t)(ch + m) * 4);
    wt[m][0] = wm.x; wt[m][1] = wm.y; wt[m][2] = wm.z; wt[m][3] = wm.w;
  }
  const unsigned short* Hrd = H + (size_t)par * (4 * 3 * CONVD);
  unsigned short*       Hwr = H + (size_t)(par ^ 1) * (4 * 3 * CONVD);
  float a0 = 0.f, a1 = 0.f, a2 = 0.f, a3 = 0.f;
  ushort4 x3 = make_ushort4(0, 0, 0, 0);
  #pragma unroll
  for (int j = 0; j < 4; ++j) {
    const int ts = tl + j - 3;
    ushort4 xu;
    if (ts >= 0) xu = *(const ushort4*)(Mseg + (size_t)(b * SEG + ts) * CONVD + ch);
    else         xu = *(const ushort4*)(Hrd + (size_t)(b * 3 + 3 + ts) * CONVD + ch);
    if (j == 3) x3 = xu;
    a0 = fmaf(bf2f(xu.x), wt[0][j], a0);
    a1 = fmaf(bf2f(xu.y), wt[1][j], a1);
    a2 = fmaf(bf2f(xu.z), wt[2][j], a2);
    a3 = fmaf(bf2f(xu.w), wt[3][j], a3);
  }
  a0 *= sigmoidf_(a0); a1 *= sigmoidf_(a1); a2 *= sigmoidf_(a2); a3 *= sigmoidf_(a3);
  ushort4 o = make_ushort4(f2bf(a0), f2bf(a1), f2bf(a2), f2bf(a3));
  *(ushort4*)(Cseg + (size_t)tok * CONVD + ch) = o;
  if (tl >= SEG - 3)
    *(ushort4*)(Hwr + (size_t)(b * 3 + tl - (SEG - 3)) * CONVD + ch) = x3;
}

// ---------------- b,a projections -> beta, g (segmented) ----------------
__global__ __launch_bounds__(256)
void ba_seg(const float* __restrict__ hs, const float* __restrict__ Wb,
            const float* __restrict__ Wa, const float* __restrict__ dtb,
            const float* __restrict__ Alog, float* __restrict__ beta,
            float* __restrict__ g, int t_off) {
  __shared__ float row[2048];
  __shared__ float red[4][64];
  const int tok = blockIdx.x;                 // local 0..SEGTOK-1
  const int tid = threadIdx.x;
  const float* hr = hs + (size_t)gmap(tok, t_off) * HID;
  for (int i = tid; i < 512; i += 256) ((float4*)row)[i] = ((const float4*)hr)[i];
  __syncthreads();
  const int o = tid & 63, kg = tid >> 6;
  const float* W = (o < 32) ? Wb : Wa;
  const int c = o & 31;
  float s = 0.f;
  const int k0 = kg * 512;
  for (int k = k0; k < k0 + 512; ++k) s = fmaf(row[k], W[(size_t)k * 32 + c], s);
  red[kg][o] = s;
  __syncthreads();
  if (tid < 64) {
    float v = red[0][tid] + red[1][tid] + red[2][tid] + red[3][tid];
    if (tid < 32) {
      beta[(size_t)tok * 32 + tid] = 1.f / (1.f + __expf(-v));
    } else {
      const int c2 = tid - 32;
      const float x = v + dtb[c2];
      const float sp = (x > 20.f) ? x : log1pf(__expf(x));
      g[(size_t)tok * 32 + c2] = -__expf(Alog[c2]) * sp;
    }
  }
}

// ---------------- gated delta rule core (bf16 I/O, fp32 internal, S in global) ----------------
// grid: 256 blocks = ((b*32+h)*2 + half) ; 512 threads
__global__ __launch_bounds__(512, 1)
void core_seg(const unsigned short* __restrict__ Cseg, const float* __restrict__ gbuf,
              const float* __restrict__ bbuf, unsigned short* __restrict__ Oseg,
              float* __restrict__ Sstate, int seg) {
  __shared__ float St[64][132];   // S^T : [v-col c][d]
  __shared__ float ks[64][132];
  __shared__ float qs[64][132];
  __shared__ float Am[64][68];
  __shared__ float At[64][68];
  __shared__ float vn[64][67];
  __shared__ float gcs[64], egp[64], egl[64], betas[64];

  const int tid = threadIdx.x;
  const int lane = tid & 63, wv = tid >> 6;
  const int bid = blockIdx.x;
  const int half = bid & 1, bh = bid >> 1;
  const int b = bh >> 5, h = bh & 31, hk = h >> 1;

  const unsigned short* qg = Cseg + (size_t)b * SEG * CONVD + (size_t)hk * 128;
  const unsigned short* kg = qg + 2048;
  const unsigned short* vg = Cseg + (size_t)b * SEG * CONVD + 4096 + (size_t)h * 128 + half * 64;
  const float* gg = gbuf + (size_t)b * SEG * 32 + h;
  const float* bb = bbuf + (size_t)b * SEG * 32 + h;
  unsigned short* og = Oseg + (size_t)b * SEG * VDIM + (size_t)h * 128 + half * 64;
  float* Sg = Sstate + (size_t)bid * 8192;

  if (seg == 0) {
    for (int i = tid; i < 64 * 132; i += 512) (&St[0][0])[i] = 0.f;
  } else {
    for (int i = tid; i < 8192; i += 512) St[i >> 7][i & 127] = Sg[i];
  }
  __syncthreads();

  for (int n = 0; n < SEG / 64; ++n) {
    const int t0 = n * 64;
    // ---------- load: g-scan + normalized q,k ----------
    if (wv == 0) {
      float gv = gg[(size_t)(t0 + lane) * 32];
      #pragma unroll
      for (int off = 1; off < 64; off <<= 1) {
        float u = __shfl_up(gv, off);
        if (lane >= off) gv += u;
      }
      const float gl = __shfl(gv, 63);
      gcs[lane] = gv;
      egp[lane] = __expf(gv);
      egl[lane] = __expf(gl - gv);
      betas[lane] = bb[(size_t)(t0 + lane) * 32];
    }
    {
      const int r = tid >> 3, j = tid & 7;
      const unsigned short* krow = kg + (size_t)(t0 + r) * CONVD + j * 16;
      const unsigned short* qrow = qg + (size_t)(t0 + r) * CONVD + j * 16;
      ushort8_t ku0 = *(const ushort8_t*)krow;
      ushort8_t ku1 = *(const ushort8_t*)(krow + 8);
      ushort8_t qu0 = *(const ushort8_t*)qrow;
      ushort8_t qu1 = *(const ushort8_t*)(qrow + 8);
      float kf[16], qf[16];
      #pragma unroll
      for (int u = 0; u < 8; ++u) {
        kf[u] = bf2f(ku0[u]); kf[8 + u] = bf2f(ku1[u]);
        qf[u] = bf2f(qu0[u]); qf[8 + u] = bf2f(qu1[u]);
      }
      float sk = 0.f, sq = 0.f;
      #pragma unroll
      for (int u = 0; u < 16; ++u) { sk = fmaf(kf[u], kf[u], sk); sq = fmaf(qf[u], qf[u], sq); }
      #pragma unroll
      for (int off = 1; off < 8; off <<= 1) { sk += __shfl_xor(sk, off); sq += __shfl_xor(sq, off); }
      const float rk = 1.f / sqrtf(sk + 1e-6f);
      const float rq = 0.08838834764831845f / sqrtf(sq + 1e-6f);  // * Dk^-0.5
      #pragma unroll
      for (int u = 0; u < 4; ++u) {
        float4 tk = make_float4(kf[u * 4] * rk, kf[u * 4 + 1] * rk, kf[u * 4 + 2] * rk, kf[u * 4 + 3] * rk);
        float4 tq = make_float4(qf[u * 4] * rq, qf[u * 4 + 1] * rq, qf[u * 4 + 2] * rq, qf[u * 4 + 3] * rq);
        *(float4*)&ks[r][j * 16 + u * 4] = tk;
        *(float4*)&qs[r][j * 16 + u * 4] = tq;
      }
    }
    __syncthreads();

    // ---------- A (strict lower) & attn (lower incl diag) ----------
    {
      const int i0 = (tid >> 5) * 4;
      const int ja = tid & 31, jb = ja + 32;
      float kk[4][2] = {{0.f}}, qk[4][2] = {{0.f}};
      #pragma unroll 8
      for (int d0 = 0; d0 < 128; d0 += 4) {
        const float4 k0 = *(const float4*)&ks[ja][d0];
        const float4 k1 = *(const float4*)&ks[jb][d0];
        #pragma unroll
        for (int r = 0; r < 4; ++r) {
          const float4 ki = *(const float4*)&ks[i0 + r][d0];
          const float4 qi = *(const float4*)&qs[i0 + r][d0];
          kk[r][0] = fmaf(ki.x, k0.x, fmaf(ki.y, k0.y, fmaf(ki.z, k0.z, fmaf(ki.w, k0.w, kk[r][0]))));
          kk[r][1] = fmaf(ki.x, k1.x, fmaf(ki.y, k1.y, fmaf(ki.z, k1.z, fmaf(ki.w, k1.w, kk[r][1]))));
          qk[r][0] = fmaf(qi.x, k0.x, fmaf(qi.y, k0.y, fmaf(qi.z, k0.z, fmaf(qi.w, k0.w, qk[r][0]))));
          qk[r][1] = fmaf(qi.x, k1.x, fmaf(qi.y, k1.y, fmaf(qi.z, k1.z, fmaf(qi.w, k1.w, qk[r][1]))));
        }
      }
      #pragma unroll
      for (int r = 0; r < 4; ++r) {
        const int i = i0 + r;
        const float gi = gcs[i], bi = betas[i];
        float e = __expf(gi - gcs[ja]);
        Am[i][ja] = (i > ja) ? -bi * e * kk[r][0] : 0.f;
        At[i][ja] = (i >= ja) ? e * qk[r][0] : 0.f;
        e = __expf(gi - gcs[jb]);
        Am[i][jb] = (i > jb) ? -bi * e * kk[r][1] : 0.f;
        At[i][jb] = (i >= jb) ? e * qk[r][1] : 0.f;
      }
    }
    // ---------- u = beta*v - (beta e^gc k) @ S ----------
    {
      const int i0 = (tid >> 5) * 4;
      const int ca = tid & 31, cb = ca + 32;
      float acc[4][2] = {{0.f}};
      #pragma unroll 8
      for (int d0 = 0; d0 < 128; d0 += 4) {
        const float4 s0 = *(const float4*)&St[ca][d0];
        const float4 s1 = *(const float4*)&St[cb][d0];
        #pragma unroll
        for (int r = 0; r < 4; ++r) {
          const float4 kr = *(const float4*)&ks[i0 + r][d0];
          acc[r][0] = fmaf(kr.x, s0.x, fmaf(kr.y, s0.y, fmaf(kr.z, s0.z, fmaf(kr.w, s0.w, acc[r][0]))));
          acc[r][1] = fmaf(kr.x, s1.x, fmaf(kr.y, s1.y, fmaf(kr.z, s1.z, fmaf(kr.w, s1.w, acc[r][1]))));
        }
      }
      #pragma unroll
      for (int r = 0; r < 4; ++r) {
        const int i = i0 + r;
        const float be = betas[i];
        const float sc = be * egp[i];
        const float v0 = bf2f(vg[(size_t)(t0 + i) * CONVD + ca]);
        const float v1 = bf2f(vg[(size_t)(t0 + i) * CONVD + cb]);
        vn[i][ca] = fmaf(be, v0, -sc * acc[r][0]);
        vn[i][cb] = fmaf(be, v1, -sc * acc[r][1]);
      }
    }
    __syncthreads();

    // ---------- forward substitution: v_new = (I-A)^{-1} u ----------
    {
      const int c = wv * 8 + (lane >> 3);
      const int jl = lane & 7;
      for (int i = 1; i < 64; ++i) {
        float p = 0.f;
        for (int j = jl; j < i; j += 8) p = fmaf(Am[i][j], vn[j][c], p);
        p += __shfl_xor(p, 1);
        p += __shfl_xor(p, 2);
        p += __shfl_xor(p, 4);
        if (jl == 0) vn[i][c] += p;
      }
    }
    __syncthreads();

    // ---------- out = (q e^gc) @ S + attn @ v_new ----------
    {
      const int i0 = (tid >> 5) * 4;
      const int ca = tid & 31, cb = ca + 32;
      float ov[4][2] = {{0.f}};
      #pragma unroll 8
      for (int d0 = 0; d0 < 128; d0 += 4) {
        const float4 s0 = *(const float4*)&St[ca][d0];
        const float4 s1 = *(const float4*)&St[cb][d0];
        #pragma unroll
        for (int r = 0; r < 4; ++r) {
          const float4 qr = *(const float4*)&qs[i0 + r][d0];
          ov[r][0] = fmaf(qr.x, s0.x, fmaf(qr.y, s0.y, fmaf(qr.z, s0.z, fmaf(qr.w, s0.w, ov[r][0]))));
          ov[r][1] = fmaf(qr.x, s1.x, fmaf(qr.y, s1.y, fmaf(qr.z, s1.z, fmaf(qr.w, s1.w, ov[r][1]))));
        }
      }
      #pragma unroll
      for (int r = 0; r < 4; ++r) { ov[r][0] *= egp[i0 + r]; ov[r][1] *= egp[i0 + r]; }
      #pragma unroll 4
      for (int j0 = 0; j0 < 64; j0 += 4) {
        float a_[4][4];
        #pragma unroll
        for (int r = 0; r < 4; ++r) {
          float4 t = *(const float4*)&At[i0 + r][j0];
          a_[r][0] = t.x; a_[r][1] = t.y; a_[r][2] = t.z; a_[r][3] = t.w;
        }
        #pragma unroll
        for (int jj = 0; jj < 4; ++jj) {
          const float v0 = vn[j0 + jj][ca];
          const float v1 = vn[j0 + jj][cb];
          #pragma unroll
          for (int r = 0; r < 4; ++r) {
            ov[r][0] = fmaf(a_[r][jj], v0, ov[r][0]);
            ov[r][1] = fmaf(a_[r][jj], v1, ov[r][1]);
          }
        }
      }
      #pragma unroll
      for (int r = 0; r < 4; ++r) {
        og[(size_t)(t0 + i0 + r) * VDIM + ca] = f2bf(ov[r][0]);
        og[(size_t)(t0 + i0 + r) * VDIM + cb] = f2bf(ov[r][1]);
      }
    }
    __syncthreads();

    // ---------- S = e^gl * S + (k e^{gl-gc})^T @ v_new ----------
    {
      const int ca = tid & 31, cb = ca + 32;
      const int d0 = (tid >> 5) * 8;
      const float egall = __expf(gcs[63]);
      float accA[8] = {0.f, 0.f, 0.f, 0.f, 0.f, 0.f, 0.f, 0.f};
      float accB[8] = {0.f, 0.f, 0.f, 0.f, 0.f, 0.f, 0.f, 0.f};
      #pragma unroll 4
      for (int i = 0; i < 64; ++i) {
        const float w = egl[i];
        const float x0 = vn[i][ca] * w;
        const float x1 = vn[i][cb] * w;
        const float4 k0 = *(const float4*)&ks[i][d0];
        const float4 k1 = *(const float4*)&ks[i][d0 + 4];
        accA[0] = fmaf(x0, k0.x, accA[0]); accA[1] = fmaf(x0, k0.y, accA[1]);
        accA[2] = fmaf(x0, k0.z, accA[2]); accA[3] = fmaf(x0, k0.w, accA[3]);
        accA[4] = fmaf(x0, k1.x, accA[4]); accA[5] = fmaf(x0, k1.y, accA[5]);
        accA[6] = fmaf(x0, k1.z, accA[6]); accA[7] = fmaf(x0, k1.w, accA[7]);
        accB[0] = fmaf(x1, k0.x, accB[0]); accB[1] = fmaf(x1, k0.y, accB[1]);
        accB[2] = fmaf(x1, k0.z, accB[2]); accB[3] = fmaf(x1, k0.w, accB[3]);
        accB[4] = fmaf(x1, k1.x, accB[4]); accB[5] = fmaf(x1, k1.y, accB[5]);
        accB[6] = fmaf(x1, k1.z, accB[6]); accB[7] = fmaf(x1, k1.w, accB[7]);
      }
      float4 s;
      s = *(float4*)&St[ca][d0];
      s.x = fmaf(s.x, egall, accA[0]); s.y = fmaf(s.y, egall, accA[1]);
      s.z = fmaf(s.z, egall, accA[2]); s.w = fmaf(s.w, egall, accA[3]);
      *(float4*)&St[ca][d0] = s;
      s = *(float4*)&St[ca][d0 + 4];
      s.x = fmaf(s.x, egall, accA[4]); s.y = fmaf(s.y, egall, accA[5]);
      s.z = fmaf(s.z, egall, accA[6]); s.w = fmaf(s.w, egall, accA[7]);
      *(float4*)&St[ca][d0 + 4] = s;
      s = *(float4*)&St[cb][d0];
      s.x = fmaf(s.x, egall, accB[0]); s.y = fmaf(s.y, egall, accB[1]);
      s.z = fmaf(s.z, egall, accB[2]); s.w = fmaf(s.w, egall, accB[3]);
      *(float4*)&St[cb][d0] = s;
      s = *(float4*)&St[cb][d0 + 4];
      s.x = fmaf(s.x, egall, accB[4]); s.y = fmaf(s.y, egall, accB[5]);
      s.z = fmaf(s.z, egall, accB[6]); s.w = fmaf(s.w, egall, accB[7]);
      *(float4*)&St[cb][d0 + 4] = s;
    }
    __syncthreads();
  }

  // spill S for next segment
  for (int i = tid; i < 8192; i += 512) Sg[i] = St[i >> 7][i & 127];
}

// ---------------- gated RMSNorm (bf16 in-place on O) ----------------
__global__ __launch_bounds__(256)
void rms_seg(unsigned short* __restrict__ core, const unsigned short* __restrict__ z,
             const float* __restrict__ nw) {
  const int tid = threadIdx.x;
  const int row = blockIdx.x * 8 + (tid >> 5);   // local (tok*32+h) row
  const int lc = tid & 31;
  const size_t off = (size_t)row * 128 + lc * 4;
  ushort4 cu = *(const ushort4*)(core + off);
  ushort4 zu = *(const ushort4*)(z + off);
  float z0 = bf2f(zu.x), z1 = bf2f(zu.y), z2 = bf2f(zu.z), z3 = bf2f(zu.w);
  z0 *= sigmoidf_(z0); z1 *= sigmoidf_(z1); z2 *= sigmoidf_(z2); z3 *= sigmoidf_(z3);
  const float g0 = bf2f(cu.x) * z0, g1 = bf2f(cu.y) * z1;
  const float g2 = bf2f(cu.z) * z2, g3 = bf2f(cu.w) * z3;
  float ss = g0 * g0 + g1 * g1 + g2 * g2 + g3 * g3;
  #pragma unroll
  for (int off2 = 1; off2 < 32; off2 <<= 1) ss += __shfl_xor(ss, off2);
  const float rn = 1.f / sqrtf(ss * (1.f / 128.f) + 1e-6f);
  float4 wn = *(const float4*)(nw + lc * 4);
  ushort4 r = make_ushort4(f2bf(g0 * rn * wn.x), f2bf(g1 * rn * wn.y),
                           f2bf(g2 * rn * wn.z), f2bf(g3 * rn * wn.w));
  *(ushort4*)(core + off) = r;
}

extern "C" void kernel_launch(void* const* d_in, const int* in_sizes, int n_in,
                              void* d_out, int out_size, void* d_ws, size_t ws_size,
                              hipStream_t stream) {
  (void)in_sizes; (void)n_in; (void)out_size;
  const float* hs    = (const float*)d_in[0];
  const float* Wqkv  = (const float*)d_in[1];
  const float* Wz    = (const float*)d_in[2];
  const float* Wb    = (const float*)d_in[3];
  const float* Wa    = (const float*)d_in[4];
  const float* convw = (const float*)d_in[5];
  const float* dtb   = (const float*)d_in[6];
  const float* Alog  = (const float*)d_in[7];
  const float* normw = (const float*)d_in[8];
  const float* Wout  = (const float*)d_in[9];
  float* out = (float*)d_out;

  // workspace plan (120.5 MiB peak, < 137 MiB proven available):
  char* ws = (char*)d_ws;
  unsigned short* Wqkv_t = (unsigned short*)(ws);               // [8192][2048] bf16, 32 MiB
  unsigned short* Wz_t   = (unsigned short*)(ws + 0x2000000);   // [4096][2048] bf16, 16 MiB
  unsigned short* Wout_t = (unsigned short*)(ws + 0x3000000);   // [2048][4096] bf16, 16 MiB
  unsigned short* mixed  = (unsigned short*)(ws + 0x4000000);   // [1024][8192] bf16, 16 MiB
  unsigned short* convb  = (unsigned short*)(ws + 0x5000000);   // [1024][8192] bf16, 16 MiB
  unsigned short* zb     = (unsigned short*)(ws + 0x6000000);   // [1024][4096] bf16, 8 MiB
  unsigned short* Obuf   = (unsigned short*)(ws + 0x6800000);   // [1024][4096] bf16, 8 MiB
  float*          Sbuf   = (float*)(ws + 0x7000000);            // 256 x 64x128 fp32, 8 MiB
  float*          betab  = (float*)(ws + 0x7800000);            // 1024x32 fp32
  float*          gbuf   = (float*)(ws + 0x7820000);            // 1024x32 fp32
  unsigned short* Hbuf   = (unsigned short*)(ws + 0x7840000);   // halo ping-pong bf16
  const size_t NEED = 0x78A0000;
  if (ws_size < NEED) return;   // clean validation failure instead of OOB crash

  // weight transpose + bf16 convert (once per launch)
  wtrans<<<dim3(CONVD / 32, HID / 32), 256, 0, stream>>>(Wqkv, Wqkv_t, HID, CONVD);
  wtrans<<<dim3(VDIM / 32, HID / 32), 256, 0, stream>>>(Wz, Wz_t, HID, VDIM);
  wtrans<<<dim3(HID / 32, VDIM / 32), 256, 0, stream>>>(Wout, Wout_t, VDIM, HID);
  zero_halo<<<48, 256, 0, stream>>>((float*)Hbuf);

  for (int s = 0; s < NSEG; ++s) {
    const int t0 = s * SEG;
    // 1. mixed = bf16( hs[seg] @ Wqkv )
    gemm_bf16<0, 1, 1, 0><<<dim3(CONVD / 128, SEGTOK / 128), 256, 0, stream>>>(
        hs, Wqkv_t, mixed, CONVD, HID, t0);
    // 2. causal conv + silu (bf16, 3-token halo carry)
    conv_seg<<<(SEGTOK * 2048) / 256, 256, 0, stream>>>(mixed, convw, convb, Hbuf, s & 1);
    // 3. z = bf16( hs[seg] @ Wz )
    gemm_bf16<0, 1, 1, 0><<<dim3(VDIM / 128, SEGTOK / 128), 256, 0, stream>>>(
        hs, Wz_t, zb, VDIM, HID, t0);
    // 4. beta, g
    ba_seg<<<SEGTOK, 256, 0, stream>>>(hs, Wb, Wa, dtb, Alog, betab, gbuf, t0);
    // 5. gated delta rule core
    core_seg<<<256, 512, 0, stream>>>(convb, gbuf, betab, Obuf, Sbuf, s);
    // 6. gated RMSNorm in place on O
    rms_seg<<<(SEGTOK * 32) / 8, 256, 0, stream>>>(Obuf, zb, normw);
    // 7. out[seg] = O @ Wout
    gemm_bf16<1, 0, 0, 1><<<dim3(HID / 128, SEGTOK / 128), 256, 0, stream>>>(
        Obuf, Wout_t, out, HID, VDIM, t0);
  }
}